// Round 4
// baseline (282.501 us; speedup 1.0000x reference)
//
#include <hip/hip_runtime.h>
#include <math.h>

// STN3d, B=32, C=3, N=4096. Training-mode BN (batch stats), moment-folded.
// kA_xstats: 3x3 second moments of x  -> fold BN1 into W1 (kB)
// kC_gram:   64x64 Gram of h1 (+sum)  -> partials in ws (aliased), kR reduces
// kD_fold2:  var2[o] = w2^T C w2      -> fold BN2 into W2 (W2', b2')
// kE_layer2: single f32 GEMM 64->128 with folded weights -> relu -> bf16 hi/lo
//            transposed planes h2t[b][n][128]
// k5_layer3: bf16x3 MFMA GEMM 128->1024 (A_hi*W_hi + A_lo*W_hi + A_hi*W_lo),
//            fused f32 BN3 stats + per-(b,o) max/min, 512 blocks (2/CU)
// k_fin3_pool + 3x k_fc_bn_relu + k_final.

#define EPS 1e-5f
#define PI_F 3.1415927410125732f

typedef unsigned int u32;
typedef unsigned short u16;
typedef __bf16 bf16x8 __attribute__((ext_vector_type(8)));
typedef float f32x4 __attribute__((ext_vector_type(4)));

__device__ __forceinline__ u16 f2bf(float f) {
  u32 u = __float_as_uint(f);
  return (u16)((u + 0x7FFFu + ((u >> 16) & 1u)) >> 16);
}
__device__ __forceinline__ float bf2f(u16 h) { return __uint_as_float(((u32)h) << 16); }

// ---------------- kA: x second moments (9 sums) -----------------------------------
__global__ __launch_bounds__(256) void kA_xstats(const float* __restrict__ x,
    float* __restrict__ xst) {
  int tg = blockIdx.x * 256 + threadIdx.x;      // 0..32767 (quads of points)
  int b = tg >> 10, nq = (tg & 1023) << 2;
  const float* xb = x + ((size_t)b * 3) * 4096 + nq;
  float4 a = *(const float4*)(xb);
  float4 c = *(const float4*)(xb + 4096);
  float4 d = *(const float4*)(xb + 8192);
  float p[9];
  p[0] = (a.x + a.y) + (a.z + a.w);
  p[1] = (c.x + c.y) + (c.z + c.w);
  p[2] = (d.x + d.y) + (d.z + d.w);
  p[3] = fmaf(a.x,a.x, fmaf(a.y,a.y, fmaf(a.z,a.z, a.w*a.w)));
  p[4] = fmaf(a.x,c.x, fmaf(a.y,c.y, fmaf(a.z,c.z, a.w*c.w)));
  p[5] = fmaf(a.x,d.x, fmaf(a.y,d.y, fmaf(a.z,d.z, a.w*d.w)));
  p[6] = fmaf(c.x,c.x, fmaf(c.y,c.y, fmaf(c.z,c.z, c.w*c.w)));
  p[7] = fmaf(c.x,d.x, fmaf(c.y,d.y, fmaf(c.z,d.z, c.w*d.w)));
  p[8] = fmaf(d.x,d.x, fmaf(d.y,d.y, fmaf(d.z,d.z, d.w*d.w)));
  #pragma unroll
  for (int k = 0; k < 9; ++k) {
    #pragma unroll
    for (int s = 1; s < 64; s <<= 1) p[k] += __shfl_xor(p[k], s);
  }
  if ((threadIdx.x & 63) == 0) {
    #pragma unroll
    for (int k = 0; k < 9; ++k) atomicAdd(&xst[k], p[k]);
  }
}

// ---------------- kB: fold BN1 into W1 --------------------------------------------
__global__ void kB_fold1(const float* __restrict__ xst,
    const float* __restrict__ w1, const float* __restrict__ b1,
    const float* __restrict__ g1, const float* __restrict__ be1,
    float* __restrict__ w1f, float* __restrict__ b1f) {
  int o = threadIdx.x;   // 64
  const float inv = 1.f / 131072.f;
  float mx = xst[0]*inv, my = xst[1]*inv, mz = xst[2]*inv;
  float cxx = xst[3]*inv - mx*mx, cxy = xst[4]*inv - mx*my, cxz = xst[5]*inv - mx*mz;
  float cyy = xst[6]*inv - my*my, cyz = xst[7]*inv - my*mz, czz = xst[8]*inv - mz*mz;
  float wa = w1[o*3], wb = w1[o*3+1], wc = w1[o*3+2];
  float mu = fmaf(wa, mx, fmaf(wb, my, fmaf(wc, mz, b1[o])));
  float var = wa*wa*cxx + wb*wb*cyy + wc*wc*czz
            + 2.f*(wa*wb*cxy + wa*wc*cxz + wb*wc*cyz);
  float s = g1[o] * rsqrtf(var + EPS);
  w1f[o*3]   = s*wa;
  w1f[o*3+1] = s*wb;
  w1f[o*3+2] = s*wc;
  b1f[o] = be1[o] + s*(b1[o] - mu);   // h1 = relu(w1f.x + b1f)
}

// ---------------- kC: Gram of h1 (64x64) + column sums ----------------------------
// 256 blocks x 256 thr; each block: 8 tiles of 64 points; partials -> gram_part.
__global__ __launch_bounds__(256) void kC_gram(const float* __restrict__ x,
    const float* __restrict__ w1f, const float* __restrict__ b1f,
    float* __restrict__ gram_part, float* __restrict__ m1v) {
  __shared__ float xs[3][64];
  __shared__ float tile[64][64];
  __shared__ float mred[256];
  int t = threadIdx.x;
  int ch = t & 63;
  float wa = w1f[ch*3], wb = w1f[ch*3+1], wc = w1f[ch*3+2], bf = b1f[ch];
  int ti = t & 7, tj = (t >> 3) & 7, ph = t >> 6;
  int i0 = ti << 3, j0 = tj << 3, p0 = ph << 4;
  float gacc[8][8];
  #pragma unroll
  for (int a = 0; a < 8; ++a)
    #pragma unroll
    for (int c = 0; c < 8; ++c) gacc[a][c] = 0.f;
  float msum = 0.f;
  for (int it = 0; it < 8; ++it) {
    int tile_id = blockIdx.x * 8 + it;
    int bb = tile_id >> 6, n0 = (tile_id & 63) << 6;
    if (t < 192) { int c = t >> 6, n = t & 63; xs[c][n] = x[((size_t)bb*3 + c)*4096 + n0 + n]; }
    __syncthreads();
    #pragma unroll
    for (int r = 0; r < 16; ++r) {        // h1 tile [pt][ch]
      int pt = (r << 2) | (t >> 6);
      float v = fmaxf(fmaf(wa, xs[0][pt], fmaf(wb, xs[1][pt], fmaf(wc, xs[2][pt], bf))), 0.f);
      tile[pt][ch] = v;
      msum += v;
    }
    __syncthreads();
    #pragma unroll 4
    for (int q = 0; q < 16; ++q) {
      int pt = p0 + q;
      float4 a0 = *(const float4*)(&tile[pt][i0]);
      float4 a1 = *(const float4*)(&tile[pt][i0 + 4]);
      float4 c0 = *(const float4*)(&tile[pt][j0]);
      float4 c1 = *(const float4*)(&tile[pt][j0 + 4]);
      float ai[8] = {a0.x,a0.y,a0.z,a0.w, a1.x,a1.y,a1.z,a1.w};
      float aj[8] = {c0.x,c0.y,c0.z,c0.w, c1.x,c1.y,c1.z,c1.w};
      #pragma unroll
      for (int a = 0; a < 8; ++a)
        #pragma unroll
        for (int c = 0; c < 8; ++c) gacc[a][c] = fmaf(ai[a], aj[c], gacc[a][c]);
    }
    __syncthreads();
  }
  // m1 partial reduce
  mred[t] = msum;
  __syncthreads();
  if (t < 64) atomicAdd(&m1v[t], mred[t] + mred[t+64] + mred[t+128] + mred[t+192]);
  // reduce the 4 point-groups in LDS, then plain-store partials
  float* gl = &tile[0][0];   // 4096 floats
  if (ph == 0) {
    #pragma unroll
    for (int a = 0; a < 8; ++a)
      #pragma unroll
      for (int c = 0; c < 8; ++c) gl[(i0+a)*64 + j0 + c] = gacc[a][c];
  }
  __syncthreads();
  #pragma unroll
  for (int p = 1; p < 4; ++p) {
    if (ph == p) {
      #pragma unroll
      for (int a = 0; a < 8; ++a)
        #pragma unroll
        for (int c = 0; c < 8; ++c) gl[(i0+a)*64 + j0 + c] += gacc[a][c];
    }
    __syncthreads();
  }
  float* gp = gram_part + (size_t)blockIdx.x * 4096;
  #pragma unroll
  for (int r = 0; r < 16; ++r) gp[r*256 + t] = gl[r*256 + t];
}

// ---------------- kR: reduce gram partials ----------------------------------------
__global__ __launch_bounds__(256) void kR_gramred(const float* __restrict__ gram_part,
    float* __restrict__ gram) {
  int cell = blockIdx.x * 256 + threadIdx.x;    // 4096
  float s = 0.f;
  for (int blk = 0; blk < 256; ++blk) s += gram_part[(size_t)blk*4096 + cell];
  gram[cell] = s;
}

// ---------------- kD: fold BN2 into W2 --------------------------------------------
__global__ void kD_fold2(const float* __restrict__ gram, const float* __restrict__ m1v,
    const float* __restrict__ w2, const float* __restrict__ b2,
    const float* __restrict__ g2, const float* __restrict__ be2,
    float* __restrict__ w2f, float* __restrict__ b2f) {
  __shared__ float wrow[64];
  int o = blockIdx.x, i = threadIdx.x;          // 128 blocks x 64 thr
  wrow[i] = w2[o*64 + i];
  __syncthreads();
  const float inv = 1.f / 131072.f;
  float si = 0.f;
  #pragma unroll 8
  for (int j = 0; j < 64; ++j) si = fmaf(wrow[j], gram[j*64 + i], si);  // symmetric G
  float qi = wrow[i] * si;
  float di = wrow[i] * (m1v[i] * inv);
  #pragma unroll
  for (int d2 = 1; d2 < 64; d2 <<= 1) { qi += __shfl_xor(qi, d2); di += __shfl_xor(di, d2); }
  float mu2 = di + b2[o];
  float var = qi*inv - di*di;
  float s = g2[o] * rsqrtf(var + EPS);
  w2f[o*64 + i] = s * wrow[i];
  if (i == 0) b2f[o] = be2[o] + s*(b2[o] - mu2);
}

// ---------------- kE: layer2 GEMM (folded) -> relu -> hi/lo split, transposed -----
__global__ __launch_bounds__(256) void kE_layer2(const float* __restrict__ x,
    const float* __restrict__ w1f, const float* __restrict__ b1f,
    const float* __restrict__ w2f, const float* __restrict__ b2f,
    u16* __restrict__ h2t_hi, u16* __restrict__ h2t_lo) {
  __shared__ float xs[3][64];
  __shared__ float w1s[64][3];
  __shared__ float b1s[64];
  __shared__ float h1s[64][64];
  __shared__ float w2s[128][64];
  int t = threadIdx.x;
  int tile = blockIdx.x;
  int b = tile >> 6;
  int n0 = (tile & 63) << 6;
  if (t < 192) { int c = t >> 6, n = t & 63; xs[c][n] = x[((size_t)b*3 + c)*4096 + n0 + n]; }
  if (t < 64) {
    b1s[t] = b1f[t];
    w1s[t][0] = w1f[t*3+0]; w1s[t][1] = w1f[t*3+1]; w1s[t][2] = w1f[t*3+2];
  }
  for (int v = t; v < 2048; v += 256) {
    int row = v >> 4, c4 = (v & 15) << 2;
    int sw = ((row >> 3) & 3) << 2;
    *(float4*)(&w2s[row][c4 ^ sw]) = *(const float4*)(w2f + row*64 + c4);
  }
  __syncthreads();
  for (int idx = t; idx < 4096; idx += 256) {
    int o = idx >> 6, n = idx & 63;
    h1s[o][n] = fmaxf(fmaf(w1s[o][0], xs[0][n], fmaf(w1s[o][1], xs[1][n], fmaf(w1s[o][2], xs[2][n], b1s[o]))), 0.f);
  }
  __syncthreads();
  int to = t & 15, tn = t >> 4;         // swapped map -> coalesced transposed stores
  int ob = to << 3, nb = tn << 2;
  int swz = (to & 3) << 2;
  float acc[8][4];
  #pragma unroll
  for (int i = 0; i < 8; ++i) { float bb = b2f[ob+i]; acc[i][0]=bb; acc[i][1]=bb; acc[i][2]=bb; acc[i][3]=bb; }
  #pragma unroll 2
  for (int k0 = 0; k0 < 64; k0 += 4) {
    float4 bv[4];
    #pragma unroll
    for (int kk = 0; kk < 4; ++kk) bv[kk] = *(const float4*)(&h1s[k0+kk][nb]);
    #pragma unroll
    for (int i = 0; i < 8; ++i) {
      float4 av = *(const float4*)(&w2s[ob+i][k0 ^ swz]);
      const float* ap = (const float*)&av;
      #pragma unroll
      for (int kk = 0; kk < 4; ++kk) {
        const float* bp = (const float*)&bv[kk];
        #pragma unroll
        for (int j = 0; j < 4; ++j) acc[i][j] = fmaf(ap[kk], bp[j], acc[i][j]);
      }
    }
  }
  #pragma unroll
  for (int j = 0; j < 4; ++j) {
    int n = n0 + nb + j;
    u32 hiw[4], low[4];
    #pragma unroll
    for (int p = 0; p < 4; ++p) {
      float v0 = fmaxf(acc[2*p][j],   0.f);
      float v1 = fmaxf(acc[2*p+1][j], 0.f);
      u16 h0 = f2bf(v0), h1 = f2bf(v1);
      u16 l0 = f2bf(v0 - bf2f(h0)), l1 = f2bf(v1 - bf2f(h1));
      hiw[p] = (u32)h0 | ((u32)h1 << 16);
      low[p] = (u32)l0 | ((u32)l1 << 16);
    }
    size_t idx = (((size_t)(b << 12) + n) << 7) + ob;
    *(uint4*)(h2t_hi + idx) = make_uint4(hiw[0], hiw[1], hiw[2], hiw[3]);
    *(uint4*)(h2t_lo + idx) = make_uint4(low[0], low[1], low[2], low[3]);
  }
}

// ---------------- k5: bf16x3 MFMA GEMM 128ch -> 1024, fused stats + max/min -------
// 512 blocks (2/CU), 512 thr (8 waves). Block = (b, 128-o tile, n-half); 32 chunks.
__global__ __launch_bounds__(512, 2) void k5_layer3(
    const u16* __restrict__ h2t_hi, const u16* __restrict__ h2t_lo,
    const float* __restrict__ w3,
    float* __restrict__ sum3, float* __restrict__ sq3,
    float* __restrict__ maxv, float* __restrict__ minv) {
  __shared__ __align__(16) char smem[65536];
  const int t = threadIdx.x;
  const int lane = t & 63;
  const int wid = t >> 6;
  const int wo = wid & 3;             // o quarter (32 o)
  const int wn = wid >> 2;            // n half of the 64-pt chunk
  const int id = blockIdx.x;
  const int xcd = id & 7, idx = id >> 3;
  const int b = (xcd << 2) | (idx >> 4);     // 16 blocks of one b share an XCD
  const int otile = (idx >> 1) & 7;
  const int half = idx & 1;
  const int kb2 = (lane >> 4) << 4;

  // ---- prologue: W3 tile f32 -> bf16 hi (0:32K) + lo (32K:64K), swizzled
  {
    const float* wbase = w3 + ((size_t)otile << 14);
    #pragma unroll
    for (int i = 0; i < 2; ++i) {
      int v = (i << 9) | t;
      int row = v >> 3;
      int c = (v & 7) << 4;
      const float* src = wbase + (row << 7) + c;
      float4 f0 = *(const float4*)(src);
      float4 f1 = *(const float4*)(src + 4);
      float4 f2 = *(const float4*)(src + 8);
      float4 f3 = *(const float4*)(src + 12);
      float fv[16] = {f0.x,f0.y,f0.z,f0.w, f1.x,f1.y,f1.z,f1.w,
                      f2.x,f2.y,f2.z,f2.w, f3.x,f3.y,f3.z,f3.w};
      u32 hw[8], lw[8];
      #pragma unroll
      for (int p = 0; p < 8; ++p) {
        u16 h0 = f2bf(fv[2*p]), h1 = f2bf(fv[2*p+1]);
        u16 l0 = f2bf(fv[2*p] - bf2f(h0)), l1 = f2bf(fv[2*p+1] - bf2f(h1));
        hw[p] = (u32)h0 | ((u32)h1 << 16);
        lw[p] = (u32)l0 | ((u32)l1 << 16);
      }
      int byte = (row << 8) | (c << 1);
      int sw = (row & 7) << 4;
      *(uint4*)(smem + (byte ^ sw))                = make_uint4(hw[0],hw[1],hw[2],hw[3]);
      *(uint4*)(smem + ((byte | 16) ^ sw))         = make_uint4(hw[4],hw[5],hw[6],hw[7]);
      *(uint4*)(smem + 32768 + (byte ^ sw))        = make_uint4(lw[0],lw[1],lw[2],lw[3]);
      *(uint4*)(smem + 32768 + ((byte | 16) ^ sw)) = make_uint4(lw[4],lw[5],lw[6],lw[7]);
    }
  }
  __syncthreads();

  // ---- W3 frags -> registers: o = wo*32 + of*16 + (lane&15)
  bf16x8 wf_hi[4][2], wf_lo[4][2];
  #pragma unroll
  for (int of = 0; of < 2; ++of) {
    int row = (wo << 5) | (of << 4) | (lane & 15);
    int sw = (row & 7) << 4;
    #pragma unroll
    for (int ks = 0; ks < 4; ++ks) {
      int a = ((row << 8) | (ks << 6) | kb2) ^ sw;
      wf_hi[ks][of] = *(const bf16x8*)(smem + a);
      wf_lo[ks][of] = *(const bf16x8*)(smem + 32768 + a);
    }
  }
  __syncthreads();

  // ---- staging offsets (chunk-invariant)
  const size_t gbase = ((size_t)b << 19) | ((size_t)half << 18);
  int ldsu[2], goff[2];
  #pragma unroll
  for (int i = 0; i < 2; ++i) {
    ldsu[i] = (wid << 11) | (i << 10);
    int Lb = ldsu[i] | (lane << 4);
    int gb = Lb ^ (((Lb >> 8) & 7) << 4);
    goff[i] = gb >> 1;
  }
  auto STAGE = [&](int c, int p) {
    const u16* gh = h2t_hi + gbase + ((size_t)c << 13);
    const u16* gl = h2t_lo + gbase + ((size_t)c << 13);
    char* lb = smem + (p << 15);
    #pragma unroll
    for (int i = 0; i < 2; ++i) {
      __builtin_amdgcn_global_load_lds(
          (const __attribute__((address_space(1))) u32*)(gh + goff[i]),
          (__attribute__((address_space(3))) u32*)(lb + ldsu[i]), 16, 0, 0);
      __builtin_amdgcn_global_load_lds(
          (const __attribute__((address_space(1))) u32*)(gl + goff[i]),
          (__attribute__((address_space(3))) u32*)(lb + 16384 + ldsu[i]), 16, 0, 0);
    }
  };

  int a_pre[2], a_sw[2];
  #pragma unroll
  for (int nf = 0; nf < 2; ++nf) {
    int n = (wn << 5) | (nf << 4) | (lane & 15);
    a_pre[nf] = (n << 8) | kb2;
    a_sw[nf] = (n & 7) << 4;
  }

  STAGE(0, 0);
  __syncthreads();

  f32x4 acc[2][2];
  float rs[2] = {0.f,0.f};
  float rq[2] = {0.f,0.f};
  float rmx[2] = {-3.4e38f,-3.4e38f};
  float rmn[2] = { 3.4e38f, 3.4e38f};
  const f32x4 zero4 = {0.f,0.f,0.f,0.f};

  for (int c = 0; c < 32; ++c) {
    int p = c & 1;
    if (c < 31) STAGE(c + 1, p ^ 1);
    const char* bufb = smem + (p << 15);
    __builtin_amdgcn_s_setprio(1);
    #pragma unroll
    for (int ks = 0; ks < 4; ++ks) {
      int a0 = (a_pre[0] | (ks << 6)) ^ a_sw[0];
      int a1 = (a_pre[1] | (ks << 6)) ^ a_sw[1];
      bf16x8 a0h = *(const bf16x8*)(bufb + a0);
      bf16x8 a1h = *(const bf16x8*)(bufb + a1);
      bf16x8 a0l = *(const bf16x8*)(bufb + 16384 + a0);
      bf16x8 a1l = *(const bf16x8*)(bufb + 16384 + a1);
      #pragma unroll
      for (int of = 0; of < 2; ++of) {
        f32x4 c0 = (ks == 0) ? zero4 : acc[0][of];
        f32x4 c1 = (ks == 0) ? zero4 : acc[1][of];
        c0 = __builtin_amdgcn_mfma_f32_16x16x32_bf16(a0l, wf_hi[ks][of], c0, 0, 0, 0);
        c1 = __builtin_amdgcn_mfma_f32_16x16x32_bf16(a1l, wf_hi[ks][of], c1, 0, 0, 0);
        c0 = __builtin_amdgcn_mfma_f32_16x16x32_bf16(a0h, wf_lo[ks][of], c0, 0, 0, 0);
        c1 = __builtin_amdgcn_mfma_f32_16x16x32_bf16(a1h, wf_lo[ks][of], c1, 0, 0, 0);
        acc[0][of] = __builtin_amdgcn_mfma_f32_16x16x32_bf16(a0h, wf_hi[ks][of], c0, 0, 0, 0);
        acc[1][of] = __builtin_amdgcn_mfma_f32_16x16x32_bf16(a1h, wf_hi[ks][of], c1, 0, 0, 0);
      }
    }
    __builtin_amdgcn_s_setprio(0);
    #pragma unroll
    for (int of = 0; of < 2; ++of) {
      #pragma unroll
      for (int nf = 0; nf < 2; ++nf) {
        f32x4 v = acc[nf][of];
        rs[of] += (v[0] + v[1]) + (v[2] + v[3]);
        rq[of] = fmaf(v[0],v[0], fmaf(v[1],v[1], fmaf(v[2],v[2], fmaf(v[3],v[3], rq[of]))));
        rmx[of] = fmaxf(rmx[of], fmaxf(fmaxf(v[0],v[1]), fmaxf(v[2],v[3])));
        rmn[of] = fminf(rmn[of], fminf(fminf(v[0],v[1]), fminf(v[2],v[3])));
      }
    }
    __syncthreads();
  }

  #pragma unroll
  for (int of = 0; of < 2; ++of) {
    rs[of] += __shfl_xor(rs[of], 16); rs[of] += __shfl_xor(rs[of], 32);
    rq[of] += __shfl_xor(rq[of], 16); rq[of] += __shfl_xor(rq[of], 32);
    rmx[of] = fmaxf(rmx[of], __shfl_xor(rmx[of], 16)); rmx[of] = fmaxf(rmx[of], __shfl_xor(rmx[of], 32));
    rmn[of] = fminf(rmn[of], __shfl_xor(rmn[of], 16)); rmn[of] = fminf(rmn[of], __shfl_xor(rmn[of], 32));
  }
  float* part = (float*)smem;   // [2 wn][128 o][4]
  if (lane < 16) {
    #pragma unroll
    for (int of = 0; of < 2; ++of) {
      int ol = (wo << 5) | (of << 4) | lane;
      float* pp = part + (((wn << 7) | ol) << 2);
      pp[0] = rs[of]; pp[1] = rq[of]; pp[2] = rmx[of]; pp[3] = rmn[of];
    }
  }
  __syncthreads();
  if (t < 128) {
    float S = 0.f, Q = 0.f, MX = -3.4e38f, MN = 3.4e38f;
    #pragma unroll
    for (int wq = 0; wq < 2; ++wq) {
      const float* pp = part + (((wq << 7) | t) << 2);
      S += pp[0]; Q += pp[1]; MX = fmaxf(MX, pp[2]); MN = fminf(MN, pp[3]);
    }
    int go = (((half << 5) | b) << 10) | (otile << 7) | t;
    sum3[go] = S; sq3[go] = Q; maxv[go] = MX; minv[go] = MN;
  }
}

// ---------------- finalize stats3 (+bias fold) + pooled ---------------------------
__global__ void k_fin3_pool(const float* __restrict__ sum3, const float* __restrict__ sq3,
    const float* __restrict__ maxv, const float* __restrict__ minv,
    const float* __restrict__ b3,
    const float* __restrict__ g, const float* __restrict__ be, float* __restrict__ pool) {
  int o = blockIdx.x*256 + threadIdx.x;
  float S = 0.f, Q = 0.f;
  for (int h = 0; h < 2; ++h)
    for (int b = 0; b < 32; ++b) { int gi = (((h<<5)|b)<<10) | o; S += sum3[gi]; Q += sq3[gi]; }
  const float inv = 1.f/131072.f;
  float ma = S*inv;
  float m = ma + b3[o];
  float var = Q*inv - ma*ma;
  float sc = g[o]*rsqrtf(var + EPS);
  float sh = be[o] - sc*m;
  bool pos = (sc >= 0.f);
  for (int b = 0; b < 32; ++b) {
    int g0 = (b << 10) | o, g1 = ((32 + b) << 10) | o;
    float v = pos ? fmaxf(maxv[g0], maxv[g1]) : fminf(minv[g0], minv[g1]);
    pool[(b << 10) | o] = fmaxf(fmaf(sc, v + b3[o], sh), 0.f);
  }
}

// ---------------- fused FC + batch-BN + ReLU --------------------------------------
__global__ __launch_bounds__(256) void k_fc_bn_relu(const float* __restrict__ in,
    const float* __restrict__ w, const float* __restrict__ fb,
    const float* __restrict__ g, const float* __restrict__ be,
    float* __restrict__ out, int K, int F) {
  __shared__ float wrow[1024];
  __shared__ float preb[32];
  int o = blockIdx.x, t = threadIdx.x;
  for (int k = t; k < K; k += 256) wrow[k] = w[(size_t)o*K + k];
  __syncthreads();
  int b = t >> 3, j = t & 7;
  int per = K >> 3;
  const float* inb = in + (size_t)b*K + j*per;
  const float* wp  = wrow + j*per;
  float p = 0.f;
  for (int k = 0; k < per; ++k) p = fmaf(inb[k], wp[k], p);
  p += __shfl_xor(p, 1); p += __shfl_xor(p, 2); p += __shfl_xor(p, 4);
  if (j == 0) preb[b] = p + fb[o];
  __syncthreads();
  if (t < 32) {
    float v = preb[t];
    float s = v;
    #pragma unroll
    for (int d = 1; d < 32; d <<= 1) s += __shfl_xor(s, d);
    float m = s * 0.03125f;
    float dv = v - m;
    float q = dv*dv;
    #pragma unroll
    for (int d = 1; d < 32; d <<= 1) q += __shfl_xor(q, d);
    float var = q * 0.03125f;
    float sc = g[o]*rsqrtf(var + EPS);
    out[(size_t)t*F + o] = fmaxf(fmaf(sc, dv, be[o]), 0.f);
  }
}

// ---------------- angles + Euler->rotation ----------------------------------------
__global__ __launch_bounds__(128) void k_final(const float* __restrict__ h6,
    const float* __restrict__ fw4, const float* __restrict__ fb4, float* __restrict__ out) {
  __shared__ float angs[32][3];
  int t = threadIdx.x;
  if (t < 96) {
    int b = t / 3, j = t % 3;
    float p = 0.f;
    #pragma unroll 4
    for (int k = 0; k < 128; ++k) p = fmaf(h6[b*128+k], fw4[j*128+k], p);
    angs[b][j] = (p + fb4[j]) * PI_F;
  }
  __syncthreads();
  if (t < 32) {
    float a = angs[t][0], bb = angs[t][1], c = angs[t][2];
    float sa, ca; sincosf(a,  &sa, &ca);
    float sb, cb; sincosf(bb, &sb, &cb);
    float sc, cc; sincosf(c,  &sc, &cc);
    float* o9 = out + t*9;
    o9[0] = cc*cb;
    o9[1] = fmaf(cc*sb, sa, -sc*ca);
    o9[2] = fmaf(cc*sb, ca,  sc*sa);
    o9[3] = sc*cb;
    o9[4] = fmaf(sc*sb, sa,  cc*ca);
    o9[5] = fmaf(sc*sb, ca, -cc*sa);
    o9[6] = -sb;
    o9[7] = cb*sa;
    o9[8] = cb*ca;
  }
}

extern "C" void kernel_launch(void* const* d_in, const int* in_sizes, int n_in,
                              void* d_out, int out_size, void* d_ws, size_t ws_size,
                              hipStream_t stream) {
  (void)in_sizes; (void)n_in; (void)out_size; (void)ws_size;
  const float* x   = (const float*)d_in[0];
  const float* w1  = (const float*)d_in[1];
  const float* b1  = (const float*)d_in[2];
  const float* g1  = (const float*)d_in[3];
  const float* be1 = (const float*)d_in[4];
  const float* w2  = (const float*)d_in[5];
  const float* b2  = (const float*)d_in[6];
  const float* g2  = (const float*)d_in[7];
  const float* be2 = (const float*)d_in[8];
  const float* w3  = (const float*)d_in[9];
  const float* b3  = (const float*)d_in[10];
  const float* g3  = (const float*)d_in[11];
  const float* be3 = (const float*)d_in[12];
  const float* fw1 = (const float*)d_in[13];
  const float* fb1 = (const float*)d_in[14];
  const float* g4  = (const float*)d_in[15];
  const float* be4 = (const float*)d_in[16];
  const float* fw2 = (const float*)d_in[17];
  const float* fb2 = (const float*)d_in[18];
  const float* g5p = (const float*)d_in[19];
  const float* be5 = (const float*)d_in[20];
  const float* fw3 = (const float*)d_in[21];
  const float* fb3 = (const float*)d_in[22];
  const float* g6  = (const float*)d_in[23];
  const float* be6 = (const float*)d_in[24];
  const float* fw4 = (const float*)d_in[25];
  const float* fb4 = (const float*)d_in[26];

  u16* h2t_hi = (u16*)d_ws;                     // 32 MiB
  u16* h2t_lo = (u16*)d_ws + 16777216;          // 32 MiB
  float* gram_part = (float*)d_ws;              // 4 MiB, aliases h2t (pre-kE only)
  float* acc0 = (float*)d_ws + 16777216;
  float* xst  = acc0;                           // 16
  float* m1v  = acc0 + 16;                      // 64
  float* gram = acc0 + 80;                      // 4096
  float* w1f  = acc0 + 4176;                    // 192
  float* b1f  = acc0 + 4368;                    // 64
  float* w2f  = acc0 + 4432;                    // 8192
  float* b2f  = acc0 + 12624;                   // 128
  float* sum3 = acc0 + 12752;                   // 2*32*1024
  float* sq3  = acc0 + 78288;
  float* maxv = acc0 + 143824;
  float* minv = acc0 + 209360;
  float* pool = acc0 + 274896;                  // 32768
  float* h4v  = acc0 + 307664;                  // 16384
  float* h5v  = acc0 + 324048;                  // 8192
  float* h6v  = acc0 + 332240;                  // 4096

  hipMemsetAsync(acc0, 0, 80ull*4, stream);     // xst + m1v

  kA_xstats<<<128, 256, 0, stream>>>(x, xst);
  kB_fold1<<<1, 64, 0, stream>>>(xst, w1, b1, g1, be1, w1f, b1f);
  kC_gram<<<256, 256, 0, stream>>>(x, w1f, b1f, gram_part, m1v);
  kR_gramred<<<16, 256, 0, stream>>>(gram_part, gram);
  kD_fold2<<<128, 64, 0, stream>>>(gram, m1v, w2, b2, g2, be2, w2f, b2f);
  kE_layer2<<<2048, 256, 0, stream>>>(x, w1f, b1f, w2f, b2f, h2t_hi, h2t_lo);
  k5_layer3<<<512, 512, 0, stream>>>(h2t_hi, h2t_lo, w3, sum3, sq3, maxv, minv);
  k_fin3_pool<<<4, 256, 0, stream>>>(sum3, sq3, maxv, minv, b3, g3, be3, pool);
  k_fc_bn_relu<<<512, 256, 0, stream>>>(pool, fw1, fb1, g4, be4, h4v, 1024, 512);
  k_fc_bn_relu<<<256, 256, 0, stream>>>(h4v, fw2, fb2, g5p, be5, h5v, 512, 256);
  k_fc_bn_relu<<<128, 256, 0, stream>>>(h5v, fw3, fb3, g6, be6, h6v, 256, 128);
  k_final<<<1, 128, 0, stream>>>(h6v, fw4, fb4, (float*)d_out);
}